// Round 1
// baseline (1142.024 us; speedup 1.0000x reference)
//
#include <hip/hip_runtime.h>
#include <hip/hip_bf16.h>
#include <stdint.h>

// Problem constants
#define N_ROWS 131072
#define DIM    1024
#define KCL    300
#define KPAD   320
#define QCAP   131072
#define MARGIN 4.0f     // covers bf16-trunc(x) + bf16-rne(C) approx error (~13 sigma)

// ws layout (bytes)
#define WS_CT    0        // granule-tiled bf16 C^T: 655360
#define WS_CNORM 655360   // padded Cnorm, 320 f32
#define WS_QC    656640   // queue counter
#define WS_CELLS 656704   // per-row atomicMin cells, 131072 x u64 = 1 MB
#define WS_CTF   1705280  // row-major fp32 C_T [320][1024] = 1310720
#define WS_QUEUE 3016000  // refine pairs, QCAP x int2 = 1 MB

typedef float  float4_ __attribute__((ext_vector_type(4)));
typedef short  short8  __attribute__((ext_vector_type(8)));

__device__ __forceinline__ unsigned short f2bf(float f) {   // RNE f32->bf16 (prep only)
  unsigned u = __float_as_uint(f);
  return (unsigned short)((u + 0x7fffu + ((u >> 16) & 1u)) >> 16);
}
__device__ __forceinline__ unsigned ordf(float p) {         // order-preserving f32->u32
  unsigned u = __float_as_uint(p);
  return (u & 0x80000000u) ? ~u : (u | 0x80000000u);
}
__device__ __forceinline__ float iordf(unsigned v) {
  unsigned u = (v & 0x80000000u) ? (v & 0x7fffffffu) : ~v;
  return __uint_as_float(u);
}
// pack 8 fp32 -> 8 bf16 by truncation: one v_perm_b32 per pair
__device__ __forceinline__ short8 cvt8(float4_ a, float4_ b) {
  union { unsigned u[4]; short8 s; } r;
  r.u[0] = __builtin_amdgcn_perm(__float_as_uint(a[1]), __float_as_uint(a[0]), 0x07060302u);
  r.u[1] = __builtin_amdgcn_perm(__float_as_uint(a[3]), __float_as_uint(a[2]), 0x07060302u);
  r.u[2] = __builtin_amdgcn_perm(__float_as_uint(b[1]), __float_as_uint(b[0]), 0x07060302u);
  r.u[3] = __builtin_amdgcn_perm(__float_as_uint(b[3]), __float_as_uint(b[2]), 0x07060302u);
  return r.s;
}
// async 16B global -> LDS (dest = wave-uniform base + lane*16)
__device__ __forceinline__ void load_lds16(const float* g, float* l) {
  __builtin_amdgcn_global_load_lds(
      (const __attribute__((address_space(1))) void*)g,
      (__attribute__((address_space(3))) void*)l, 16, 0, 0);
}

// ---------------- Kernel A: prep tiled bf16 C^T + fp32 C_T + padded Cnorm ----
// ct elem i = (kk*320 + col)*8 + e  -> bf16(C[(kk*8+e)*300 + col])
__global__ void prep_kernel(const float* __restrict__ C, const float* __restrict__ Cn,
                            unsigned short* __restrict__ ct, float* __restrict__ cnp,
                            float* __restrict__ ctf) {
  int i = blockIdx.x * 256 + threadIdx.x;
  if (i < KPAD * DIM) {
    int e = i & 7, col = (i >> 3) % KPAD, kk = i / (KPAD * 8);
    int d = kk * 8 + e;
    float v = (col < KCL) ? C[d * KCL + col] : 0.f;
    ct[i] = f2bf(v);
    ctf[(size_t)col * DIM + d] = v;           // coalesced-read layout for refine
  } else if (i < KPAD * DIM + KPAD) {
    int col = i - KPAD * DIM;
    cnp[col] = (col < KCL) ? Cn[col] : 1e30f;
  }
}

// ---------------- Kernel B: LDS-staged, counted-vmcnt pipelined MFMA + argmin
// Block 256 thr = 4 waves, 64 rows x 320 cols. Wave w owns cols [w*80, w*80+80).
// A (x rows, fp32) staged once per block via global_load_lds into 3 rotating
// 16KB LDS buffers (wave w stages its rows [w*16, w*16+16)).
// K-loop = 16 chunks of 64 floats. Sync: raw s_barrier + counted vmcnt(14):
//   per body: issue stage(c+2)[4 loads] -> ds_read/cvt/MFMA(chunk c)
//             -> issue pb(c+1)[10 loads] -> vmcnt(14) (= stage(c+2)+pb(c+1)
//             still in flight; everything older, incl stage(c+1), retired)
//             -> s_barrier.  Never drains to 0: HBM requests span barriers.
// Chunk order rotated per block (blockIdx&15) to spread the 4KB-stride
// column windows across HBM channels. Accumulation-order rounding differences
// are covered by the refine margin.
#define LOADB(ks, c) { _Pragma("unroll") for (int c2 = 0; c2 < 5; ++c2) { \
    pb[ks][c2] = *(const short8*)(bb + ((size_t)((c) * 8 + (ks) * 4) * KPAD + c2 * 16) * 8); } }
#define STAGE(buf, cc) { _Pragma("unroll") for (int i = 0; i < 4; ++i) \
    load_lds16(gx + (cc) * 64 + i * 16, &abuf[buf][w * 1024 + i * 256]); }

__global__ __launch_bounds__(256, 2)
void gemm_kernel(const float* __restrict__ x, const unsigned short* __restrict__ ctg,
                 const float* __restrict__ cnp, int* __restrict__ out,
                 int* __restrict__ qc, int2* __restrict__ queue) {
  __shared__ __align__(16) float abuf[3][4096];   // 3 x 16KB A staging buffers
  __shared__ __align__(16) unsigned long long red[256 * 2];
  __shared__ float thr_s[64];
  const int tid = threadIdx.x;
  const int w = tid >> 6, lane = tid & 63;
  const int quad = lane >> 4, l16 = lane & 15;
  const int row0 = blockIdx.x * 64;
  const int rot = blockIdx.x & 15;

  // staging: lane covers row (w*16 + l16), 4-float unit 'quad' of each 16-float group.
  // LDS float offset = w*1024 + i*256 + lane*4  ==  rowblk*1024 + unit*64 + r*4
  const float* gx = x + (size_t)(row0 + w * 16 + l16) * DIM + quad * 4;
  const unsigned short* bb = ctg + ((size_t)quad * KPAD + w * 80 + l16) * 8;

  float4_ acc[4][5];
#pragma unroll
  for (int rt = 0; rt < 4; ++rt)
#pragma unroll
    for (int c2 = 0; c2 < 5; ++c2) acc[rt][c2] = (float4_){0.f, 0.f, 0.f, 0.f};

  short8 pb[2][5];

  // prologue: stage chunk0 -> buf0, B frags chunk0, stage chunk1 -> buf1
  STAGE(0, rot);
  LOADB(0, rot); LOADB(1, rot);
  STAGE(1, (rot + 1) & 15);
  asm volatile("s_waitcnt vmcnt(4) lgkmcnt(0)" ::: "memory");  // chunk0 ready, chunk1 in flight
  __builtin_amdgcn_s_barrier();

  int bc = 0;                        // LDS buffer holding chunk c
  for (int c = 0; c < 16; ++c) {
    const int cc = (c + rot) & 15;
    int bs = bc + 2; if (bs >= 3) bs -= 3;           // buffer for chunk c+2
    if (c + 2 < 16) STAGE(bs, (cc + 2) & 15);        // issue early, lands 2 chunks ahead

    short8 ca[2][4];
#pragma unroll
    for (int ks = 0; ks < 2; ++ks)
#pragma unroll
      for (int rt = 0; rt < 4; ++rt) {
        const int u0 = ks * 8 + quad * 2;            // 16B unit index (conflict-free banks)
        float4_ a0 = *(const float4_*)&abuf[bc][rt * 1024 + u0 * 64 + l16 * 4];
        float4_ a1 = *(const float4_*)&abuf[bc][rt * 1024 + (u0 + 1) * 64 + l16 * 4];
        ca[ks][rt] = cvt8(a0, a1);
      }
#pragma unroll
    for (int rt = 0; rt < 4; ++rt)
#pragma unroll
      for (int c2 = 0; c2 < 5; ++c2)
        acc[rt][c2] = __builtin_amdgcn_mfma_f32_16x16x32_bf16(ca[0][rt], pb[0][c2], acc[rt][c2], 0, 0, 0);
    if (c + 1 < 16) LOADB(0, (cc + 1) & 15);
#pragma unroll
    for (int rt = 0; rt < 4; ++rt)
#pragma unroll
      for (int c2 = 0; c2 < 5; ++c2)
        acc[rt][c2] = __builtin_amdgcn_mfma_f32_16x16x32_bf16(ca[1][rt], pb[1][c2], acc[rt][c2], 0, 0, 0);
    if (c + 1 < 16) LOADB(1, (cc + 1) & 15);

    // keep stage(c+2)[4] + pb(c+1)[10] in flight; everything older (incl
    // stage(c+1)) retired. lgkmcnt(0): ds_reads of buf bc done before it can
    // be overwritten (buf bc is restaged at body c+1).
    asm volatile("s_waitcnt vmcnt(14) lgkmcnt(0)" ::: "memory");
    __builtin_amdgcn_s_barrier();
    bc = (bc + 1 == 3) ? 0 : bc + 1;
  }

  // ---- epilogue: p = Cnorm - 2*s; two-min packed-key argmin ----
  float cn[5];
#pragma unroll
  for (int c2 = 0; c2 < 5; ++c2) cn[c2] = cnp[w * 80 + c2 * 16 + l16];
  float p[4][5][4];
#pragma unroll
  for (int rt = 0; rt < 4; ++rt)
#pragma unroll
    for (int c2 = 0; c2 < 5; ++c2)
#pragma unroll
      for (int r = 0; r < 4; ++r) p[rt][c2][r] = cn[c2] - 2.f * acc[rt][c2][r];

  for (int rt = 0; rt < 4; ++rt)
    for (int r = 0; r < 4; ++r) {
      unsigned long long b = ~0ull, s = ~0ull;
#pragma unroll
      for (int c2 = 0; c2 < 5; ++c2) {
        unsigned col = (unsigned)(w * 80 + c2 * 16 + l16);
        unsigned long long k = ((unsigned long long)ordf(p[rt][c2][r]) << 10) | col;
        if (k < b) { s = b; b = k; } else if (k < s) s = k;
      }
#pragma unroll
      for (int m = 1; m <= 8; m <<= 1) {
        unsigned long long ob = __shfl_xor(b, m, 16);
        unsigned long long os = __shfl_xor(s, m, 16);
        if (ob < b) { s = (b < os) ? b : os; b = ob; } else if (ob < s) s = ob;
      }
      if (l16 == 0) {
        int row = rt * 16 + quad * 4 + r;
        red[(w * 64 + row) * 2 + 0] = b;
        red[(w * 64 + row) * 2 + 1] = s;
      }
    }
  __syncthreads();
  if (tid < 64) {
    int row = tid;
    unsigned long long b = red[row * 2], s = red[row * 2 + 1];
#pragma unroll
    for (int wi = 1; wi < 4; ++wi) {
      unsigned long long a1 = red[(wi * 64 + row) * 2];
      unsigned long long a2 = red[(wi * 64 + row) * 2 + 1];
      if (a1 < b) { s = (b < a2) ? b : a2; b = a1; } else if (a1 < s) s = a1;
    }
    float p1 = iordf((unsigned)(b >> 10));
    float p2 = iordf((unsigned)(s >> 10));
    out[row0 + row] = (int)(b & 1023u);
    thr_s[row] = ((p2 - p1) < MARGIN) ? (p1 + MARGIN) : -1e38f;
  }
  __syncthreads();
  for (int rt = 0; rt < 4; ++rt)
    for (int r = 0; r < 4; ++r) {
      int row = rt * 16 + quad * 4 + r;
      float th = thr_s[row];
#pragma unroll
      for (int c2 = 0; c2 < 5; ++c2)
        if (p[rt][c2][r] < th) {
          int pos = atomicAdd(qc, 1);
          if (pos < QCAP) queue[pos] = make_int2(row0 + row, w * 80 + c2 * 16 + l16);
        }
    }
}

// ---------------- Kernel C: exact fp32 recompute (coalesced C_T reads) -------
__global__ void refine_kernel(const float* __restrict__ x, const float* __restrict__ ctf,
                              const float* __restrict__ cnp, const int* __restrict__ qc,
                              const int2* __restrict__ queue,
                              unsigned long long* __restrict__ cells) {
  int gw   = (blockIdx.x * blockDim.x + threadIdx.x) >> 6;
  int lane = threadIdx.x & 63;
  int nw   = (gridDim.x * blockDim.x) >> 6;
  int count = *qc; if (count > QCAP) count = QCAP;
  for (int i = gw; i < count; i += nw) {
    int row = queue[i].x, col = queue[i].y;
    const float4_* xr = (const float4_*)(x + (size_t)row * DIM);
    const float4_* cr = (const float4_*)(ctf + (size_t)col * DIM);
    float s = 0.f;
#pragma unroll
    for (int it = 0; it < 4; ++it) {
      float4_ a = xr[it * 64 + lane], b = cr[it * 64 + lane];
      s += a[0] * b[0] + a[1] * b[1] + a[2] * b[2] + a[3] * b[3];
    }
#pragma unroll
    for (int m = 32; m >= 1; m >>= 1) s += __shfl_xor(s, m, 64);
    float pv = cnp[col] - 2.f * s;
    unsigned long long k = ((unsigned long long)ordf(pv) << 10) | (unsigned)col;
    if (lane == 0) atomicMin(&cells[row], k);
  }
}

// ---------------- Kernel D: commit refined rows ------------------------------
__global__ void final_kernel(const unsigned long long* __restrict__ cells,
                             int* __restrict__ out) {
  int i = blockIdx.x * 256 + threadIdx.x;
  if (i < N_ROWS) {
    unsigned long long v = cells[i];
    if (v != ~0ull) out[i] = (int)(v & 1023u);
  }
}

extern "C" void kernel_launch(void* const* d_in, const int* in_sizes, int n_in,
                              void* d_out, int out_size, void* d_ws, size_t ws_size,
                              hipStream_t stream) {
  const float* x  = (const float*)d_in[0];
  const float* C  = (const float*)d_in[1];
  const float* Cn = (const float*)d_in[2];
  char* ws = (char*)d_ws;
  unsigned short*      ct    = (unsigned short*)(ws + WS_CT);
  float*               cnp   = (float*)(ws + WS_CNORM);
  int*                 qc    = (int*)(ws + WS_QC);
  unsigned long long*  cells = (unsigned long long*)(ws + WS_CELLS);
  float*               ctf   = (float*)(ws + WS_CTF);
  int2*                queue = (int2*)(ws + WS_QUEUE);
  int* out = (int*)d_out;

  hipMemsetAsync(qc, 0, 64, stream);
  hipMemsetAsync(cells, 0xFF, (size_t)N_ROWS * 8, stream);
  prep_kernel<<<(KPAD * DIM + KPAD + 255) / 256, 256, 0, stream>>>(C, Cn, ct, cnp, ctf);
  gemm_kernel<<<N_ROWS / 64, 256, 0, stream>>>(x, ct, cnp, out, qc, queue);
  refine_kernel<<<1024, 256, 0, stream>>>(x, ctf, cnp, qc, queue, cells);
  final_kernel<<<(N_ROWS + 255) / 256, 256, 0, stream>>>(cells, out);
}

// Round 2
// 816.582 us; speedup vs baseline: 1.3985x; 1.3985x over previous
//
#include <hip/hip_runtime.h>
#include <hip/hip_bf16.h>
#include <stdint.h>

// Problem constants
#define N_ROWS 131072
#define DIM    1024
#define KCL    300
#define KPAD   320
#define QCAP   49152
#define MARGIN 0.25f    // hi/lo bf16 (3-pass) residual error bound ~0.05, 5x headroom

// ws layout (bytes) — total 4064576 (same footprint as previous layout)
#define WS_CTH   0        // granule-tiled bf16 hi(C^T): 655360
#define WS_CTL   655360   // granule-tiled bf16 lo(C^T): 655360
#define WS_CNORM 1310720  // padded Cnorm, 320 f32
#define WS_QC    1312000  // queue counter
#define WS_CELLS 1312064  // per-row atomicMin cells, 131072 x u64 = 1 MB
#define WS_CTF   2360640  // row-major fp32 C_T [320][1024] = 1310720
#define WS_QUEUE 3671360  // refine pairs, QCAP x int2 = 393216

typedef float  float4_ __attribute__((ext_vector_type(4)));
typedef short  short8  __attribute__((ext_vector_type(8)));

__device__ __forceinline__ unsigned short f2bf(float f) {   // RNE f32->bf16
  unsigned u = __float_as_uint(f);
  return (unsigned short)((u + 0x7fffu + ((u >> 16) & 1u)) >> 16);
}
__device__ __forceinline__ unsigned ordf(float p) {         // order-preserving f32->u32
  unsigned u = __float_as_uint(p);
  return (u & 0x80000000u) ? ~u : (u | 0x80000000u);
}
__device__ __forceinline__ float iordf(unsigned v) {
  unsigned u = (v & 0x80000000u) ? (v & 0x7fffffffu) : ~v;
  return __uint_as_float(u);
}
// packed RNE f32x2 -> bf16x2 (no builtin on gfx950; inline asm)
__device__ __forceinline__ unsigned cvtpk(float lo, float hi) {
  unsigned r;
  asm volatile("v_cvt_pk_bf16_f32 %0, %1, %2" : "=v"(r) : "v"(lo), "v"(hi));
  return r;
}
// split 8 fp32 into bf16 hi + bf16 lo fragments (RNE both; sub is exact in f32)
__device__ __forceinline__ void mk_hilo(float4_ a0, float4_ a1, short8& h, short8& l) {
  union { unsigned u[4]; short8 s; } H, L;
  float av[8] = {a0[0], a0[1], a0[2], a0[3], a1[0], a1[1], a1[2], a1[3]};
#pragma unroll
  for (int p = 0; p < 4; ++p) {
    unsigned hw = cvtpk(av[2 * p], av[2 * p + 1]);
    H.u[p] = hw;
    float f0 = __uint_as_float(hw << 16);
    float f1 = __uint_as_float(hw & 0xffff0000u);
    L.u[p] = cvtpk(av[2 * p] - f0, av[2 * p + 1] - f1);
  }
  h = H.s; l = L.s;
}
// async 16B global -> LDS (dest = wave-uniform base + lane*16)
__device__ __forceinline__ void load_lds16(const float* g, float* l) {
  __builtin_amdgcn_global_load_lds(
      (const __attribute__((address_space(1))) void*)g,
      (__attribute__((address_space(3))) void*)l, 16, 0, 0);
}

// ---------------- Kernel A: prep tiled bf16 hi/lo C^T + fp32 C_T + Cnorm ----
// ct elem i = (kk*320 + col)*8 + e  -> bf16(C[(kk*8+e)*300 + col])
__global__ void prep_kernel(const float* __restrict__ C, const float* __restrict__ Cn,
                            unsigned short* __restrict__ cth, unsigned short* __restrict__ ctl,
                            float* __restrict__ cnp, float* __restrict__ ctf) {
  int i = blockIdx.x * 256 + threadIdx.x;
  if (i < KPAD * DIM) {
    int e = i & 7, col = (i >> 3) % KPAD, kk = i / (KPAD * 8);
    int d = kk * 8 + e;
    float v = (col < KCL) ? C[d * KCL + col] : 0.f;
    unsigned short h = f2bf(v);
    float hf = __uint_as_float((unsigned)h << 16);
    cth[i] = h;
    ctl[i] = f2bf(v - hf);
    ctf[(size_t)col * DIM + d] = v;           // coalesced-read layout for refine
  } else if (i < KPAD * DIM + KPAD) {
    int col = i - KPAD * DIM;
    cnp[col] = (col < KCL) ? Cn[col] : 1e30f;
  }
}

// ---------------- Kernel B: LDS-staged pipelined 3-pass hi/lo MFMA + argmin --
// Block 256 thr = 4 waves, 64 rows x 320 cols. Wave w owns cols [w*80, w*80+80).
// A (x rows, fp32) staged once per block via global_load_lds into 3 rotating
// 16KB LDS buffers; per chunk split in-register into bf16 hi/lo.
// acc += ah*bh + ah*bl + al*bh  (xl*cl dropped; bound ~0.05, MARGIN covers).
// Sync per body: counted vmcnt(34) = stage(c+2)[4] + pbh/pbl(c+1)[30] in
// flight; tail bodies (c>=14) drain to 0 (fixes c=14 stage(15) race).
#define LOADBH(ks, c) { _Pragma("unroll") for (int c2 = 0; c2 < 5; ++c2) { \
    pbh[ks][c2] = *(const short8*)(bbh + ((size_t)((c) * 8 + (ks) * 4) * KPAD + c2 * 16) * 8); } }
#define LOADBL(ks, c) { _Pragma("unroll") for (int c2 = 0; c2 < 5; ++c2) { \
    pbl[ks][c2] = *(const short8*)(bbl + ((size_t)((c) * 8 + (ks) * 4) * KPAD + c2 * 16) * 8); } }
#define STAGE(buf, cc) { _Pragma("unroll") for (int i = 0; i < 4; ++i) \
    load_lds16(gx + (cc) * 64 + i * 16, &abuf[buf][w * 1024 + i * 256]); }

__global__ __launch_bounds__(256, 2)
void gemm_kernel(const float* __restrict__ x, const unsigned short* __restrict__ ctgh,
                 const unsigned short* __restrict__ ctgl,
                 const float* __restrict__ cnp, int* __restrict__ out,
                 int* __restrict__ qc, int2* __restrict__ queue) {
  __shared__ __align__(16) float abuf[3][4096];   // 3 x 16KB A staging buffers
  __shared__ __align__(16) unsigned long long red[256 * 2];
  __shared__ float thr_s[64];
  const int tid = threadIdx.x;
  const int w = tid >> 6, lane = tid & 63;
  const int quad = lane >> 4, l16 = lane & 15;
  const int row0 = blockIdx.x * 64;
  const int rot = blockIdx.x & 15;

  const float* gx = x + (size_t)(row0 + w * 16 + l16) * DIM + quad * 4;
  const unsigned short* bbh = ctgh + ((size_t)quad * KPAD + w * 80 + l16) * 8;
  const unsigned short* bbl = ctgl + ((size_t)quad * KPAD + w * 80 + l16) * 8;

  float4_ acc[4][5];
#pragma unroll
  for (int rt = 0; rt < 4; ++rt)
#pragma unroll
    for (int c2 = 0; c2 < 5; ++c2) acc[rt][c2] = (float4_){0.f, 0.f, 0.f, 0.f};

  short8 pbh[2][5], pbl[2][5];

  // prologue: stage chunk0 -> buf0, B frags chunk0 (hi+lo), stage chunk1 -> buf1
  STAGE(0, rot);
  LOADBH(0, rot); LOADBH(1, rot);
  LOADBL(0, rot); LOADBL(1, rot);
  STAGE(1, (rot + 1) & 15);
  asm volatile("s_waitcnt vmcnt(4) lgkmcnt(0)" ::: "memory");  // chunk0 ready
  __builtin_amdgcn_s_barrier();

  int bc = 0;                        // LDS buffer holding chunk c
  for (int c = 0; c < 16; ++c) {
    const int cc = (c + rot) & 15;
    int bs = bc + 2; if (bs >= 3) bs -= 3;           // buffer for chunk c+2
    if (c + 2 < 16) STAGE(bs, (cc + 2) & 15);        // lands 2 chunks ahead

    short8 cah[2][4], cal[2][4];
#pragma unroll
    for (int ks = 0; ks < 2; ++ks)
#pragma unroll
      for (int rt = 0; rt < 4; ++rt) {
        const int u0 = ks * 8 + quad * 2;            // 16B unit index
        float4_ a0 = *(const float4_*)&abuf[bc][rt * 1024 + u0 * 64 + l16 * 4];
        float4_ a1 = *(const float4_*)&abuf[bc][rt * 1024 + (u0 + 1) * 64 + l16 * 4];
        mk_hilo(a0, a1, cah[ks][rt], cal[ks][rt]);
      }
    // pass 1: ah * bh
#pragma unroll
    for (int ks = 0; ks < 2; ++ks)
#pragma unroll
      for (int rt = 0; rt < 4; ++rt)
#pragma unroll
        for (int c2 = 0; c2 < 5; ++c2)
          acc[rt][c2] = __builtin_amdgcn_mfma_f32_16x16x32_bf16(cah[ks][rt], pbh[ks][c2], acc[rt][c2], 0, 0, 0);
    // pass 2: ah * bl
#pragma unroll
    for (int ks = 0; ks < 2; ++ks)
#pragma unroll
      for (int rt = 0; rt < 4; ++rt)
#pragma unroll
        for (int c2 = 0; c2 < 5; ++c2)
          acc[rt][c2] = __builtin_amdgcn_mfma_f32_16x16x32_bf16(cah[ks][rt], pbl[ks][c2], acc[rt][c2], 0, 0, 0);
    if (c + 1 < 16) { LOADBL(0, (cc + 1) & 15); LOADBL(1, (cc + 1) & 15); }
    // pass 3: al * bh
#pragma unroll
    for (int ks = 0; ks < 2; ++ks)
#pragma unroll
      for (int rt = 0; rt < 4; ++rt)
#pragma unroll
        for (int c2 = 0; c2 < 5; ++c2)
          acc[rt][c2] = __builtin_amdgcn_mfma_f32_16x16x32_bf16(cal[ks][rt], pbh[ks][c2], acc[rt][c2], 0, 0, 0);
    if (c + 1 < 16) { LOADBH(0, (cc + 1) & 15); LOADBH(1, (cc + 1) & 15); }

    // steady state: keep stage(c+2)[4] + pb(c+1)[30] in flight; everything
    // older (incl stage(c+1)) retired. Tail (c>=14): drain (stage(15) must
    // land before body 15 reads it — vmcnt(34) can't guarantee that there).
    if (c < 14) asm volatile("s_waitcnt vmcnt(34) lgkmcnt(0)" ::: "memory");
    else        asm volatile("s_waitcnt vmcnt(0) lgkmcnt(0)" ::: "memory");
    __builtin_amdgcn_s_barrier();
    bc = (bc + 1 == 3) ? 0 : bc + 1;
  }

  // ---- epilogue: p = Cnorm - 2*s; two-min packed-key argmin ----
  float cn[5];
#pragma unroll
  for (int c2 = 0; c2 < 5; ++c2) cn[c2] = cnp[w * 80 + c2 * 16 + l16];
  float p[4][5][4];
#pragma unroll
  for (int rt = 0; rt < 4; ++rt)
#pragma unroll
    for (int c2 = 0; c2 < 5; ++c2)
#pragma unroll
      for (int r = 0; r < 4; ++r) p[rt][c2][r] = cn[c2] - 2.f * acc[rt][c2][r];

  for (int rt = 0; rt < 4; ++rt)
    for (int r = 0; r < 4; ++r) {
      unsigned long long b = ~0ull, s = ~0ull;
#pragma unroll
      for (int c2 = 0; c2 < 5; ++c2) {
        unsigned col = (unsigned)(w * 80 + c2 * 16 + l16);
        unsigned long long k = ((unsigned long long)ordf(p[rt][c2][r]) << 10) | col;
        if (k < b) { s = b; b = k; } else if (k < s) s = k;
      }
#pragma unroll
      for (int m = 1; m <= 8; m <<= 1) {
        unsigned long long ob = __shfl_xor(b, m, 16);
        unsigned long long os = __shfl_xor(s, m, 16);
        if (ob < b) { s = (b < os) ? b : os; b = ob; } else if (ob < s) s = ob;
      }
      if (l16 == 0) {
        int row = rt * 16 + quad * 4 + r;
        red[(w * 64 + row) * 2 + 0] = b;
        red[(w * 64 + row) * 2 + 1] = s;
      }
    }
  __syncthreads();
  if (tid < 64) {
    int row = tid;
    unsigned long long b = red[row * 2], s = red[row * 2 + 1];
#pragma unroll
    for (int wi = 1; wi < 4; ++wi) {
      unsigned long long a1 = red[(wi * 64 + row) * 2];
      unsigned long long a2 = red[(wi * 64 + row) * 2 + 1];
      if (a1 < b) { s = (b < a2) ? b : a2; b = a1; } else if (a1 < s) s = a1;
    }
    float p1 = iordf((unsigned)(b >> 10));
    float p2 = iordf((unsigned)(s >> 10));
    out[row0 + row] = (int)(b & 1023u);
    thr_s[row] = ((p2 - p1) < MARGIN) ? (p1 + MARGIN) : -1e38f;
  }
  __syncthreads();
  for (int rt = 0; rt < 4; ++rt)
    for (int r = 0; r < 4; ++r) {
      int row = rt * 16 + quad * 4 + r;
      float th = thr_s[row];
#pragma unroll
      for (int c2 = 0; c2 < 5; ++c2)
        if (p[rt][c2][r] < th) {
          int pos = atomicAdd(qc, 1);
          if (pos < QCAP) queue[pos] = make_int2(row0 + row, w * 80 + c2 * 16 + l16);
        }
    }
}

// ---------------- Kernel C: exact fp32 recompute (coalesced C_T reads) -------
__global__ void refine_kernel(const float* __restrict__ x, const float* __restrict__ ctf,
                              const float* __restrict__ cnp, const int* __restrict__ qc,
                              const int2* __restrict__ queue,
                              unsigned long long* __restrict__ cells) {
  int gw   = (blockIdx.x * blockDim.x + threadIdx.x) >> 6;
  int lane = threadIdx.x & 63;
  int nw   = (gridDim.x * blockDim.x) >> 6;
  int count = *qc; if (count > QCAP) count = QCAP;
  for (int i = gw; i < count; i += nw) {
    int row = queue[i].x, col = queue[i].y;
    const float4_* xr = (const float4_*)(x + (size_t)row * DIM);
    const float4_* cr = (const float4_*)(ctf + (size_t)col * DIM);
    float s = 0.f;
#pragma unroll
    for (int it = 0; it < 4; ++it) {
      float4_ a = xr[it * 64 + lane], b = cr[it * 64 + lane];
      s += a[0] * b[0] + a[1] * b[1] + a[2] * b[2] + a[3] * b[3];
    }
#pragma unroll
    for (int m = 32; m >= 1; m >>= 1) s += __shfl_xor(s, m, 64);
    float pv = cnp[col] - 2.f * s;
    unsigned long long k = ((unsigned long long)ordf(pv) << 10) | (unsigned)col;
    if (lane == 0) atomicMin(&cells[row], k);
  }
}

// ---------------- Kernel D: commit refined rows ------------------------------
__global__ void final_kernel(const unsigned long long* __restrict__ cells,
                             int* __restrict__ out) {
  int i = blockIdx.x * 256 + threadIdx.x;
  if (i < N_ROWS) {
    unsigned long long v = cells[i];
    if (v != ~0ull) out[i] = (int)(v & 1023u);
  }
}

extern "C" void kernel_launch(void* const* d_in, const int* in_sizes, int n_in,
                              void* d_out, int out_size, void* d_ws, size_t ws_size,
                              hipStream_t stream) {
  const float* x  = (const float*)d_in[0];
  const float* C  = (const float*)d_in[1];
  const float* Cn = (const float*)d_in[2];
  char* ws = (char*)d_ws;
  unsigned short*      cth   = (unsigned short*)(ws + WS_CTH);
  unsigned short*      ctl   = (unsigned short*)(ws + WS_CTL);
  float*               cnp   = (float*)(ws + WS_CNORM);
  int*                 qc    = (int*)(ws + WS_QC);
  unsigned long long*  cells = (unsigned long long*)(ws + WS_CELLS);
  float*               ctf   = (float*)(ws + WS_CTF);
  int2*                queue = (int2*)(ws + WS_QUEUE);
  int* out = (int*)d_out;

  hipMemsetAsync(qc, 0, 64, stream);
  hipMemsetAsync(cells, 0xFF, (size_t)N_ROWS * 8, stream);
  prep_kernel<<<(KPAD * DIM + KPAD + 255) / 256, 256, 0, stream>>>(C, Cn, cth, ctl, cnp, ctf);
  gemm_kernel<<<N_ROWS / 64, 256, 0, stream>>>(x, cth, ctl, cnp, out, qc, queue);
  refine_kernel<<<1024, 256, 0, stream>>>(x, ctf, cnp, qc, queue, cells);
  final_kernel<<<(N_ROWS + 255) / 256, 256, 0, stream>>>(cells, out);
}